// Round 5
// baseline (238.294 us; speedup 1.0000x reference)
//
#include <hip/hip_runtime.h>
#include <hip/hip_bf16.h>
#include <hip/hip_cooperative_groups.h>

namespace cg = cooperative_groups;

// Problem constants
#define BB 8
#define SS 2048
#define DD 1024
#define OO 1024
#define MM (BB * SS)   // 16384
#define KK DD          // 1024
#define NN OO          // 1024
#define CC 64          // chunks
#define LL 32          // chunk length (CC*LL == SS)

typedef __bf16 bf16x8 __attribute__((ext_vector_type(8)));
typedef __bf16 bf16x4 __attribute__((ext_vector_type(4)));
typedef float floatx4 __attribute__((ext_vector_type(4)));

__device__ __forceinline__ float4 fma4(float4 h, float4 a, float4 v) {
    h.x = fmaf(h.x, a.x, v.x);
    h.y = fmaf(h.y, a.y, v.y);
    h.z = fmaf(h.z, a.z, v.z);
    h.w = fmaf(h.w, a.w, v.w);
    return h;
}

// ---------------- Fused scan kernel (cooperative) ----------------
// 512 blocks x 256 threads, all co-resident (LDS 4.2KB, VGPR ~80 -> >=6
// blocks/CU capacity >> 2 needed). Phase 1: per-chunk carry (reads x from
// HBM) + BC transpose (2 tiles/block). grid.sync. Phase 2: chunk-prefix
// from carries, rescan x (now L3-resident after phase 1 -> no 2nd HBM
// pass), emit hs bf16. Identical arithmetic/rounding to the previous
// 2-kernel version -> absmax unchanged.
__global__ __launch_bounds__(256) void scan_full(const float* __restrict__ x,
                                                 const float* __restrict__ A,
                                                 float* __restrict__ carry,
                                                 const float* __restrict__ BC,
                                                 __bf16* __restrict__ BCt,
                                                 __bf16* __restrict__ hs) {
    __shared__ float tile[32][33];
    const int id = blockIdx.x;      // 0..511 == (b,c)
    const int c = id & (CC - 1);
    const int b = id >> 6;
    const int i4 = threadIdx.x;     // float4 index over D (0..255)
    const float4 a = ((const float4*)A)[i4];
    const size_t base = ((size_t)b * SS + (size_t)c * LL) * DD;
    const float4* xp = (const float4*)(x + base) + i4;

    // ---- phase 1a: chunk carry (h over LL steps from h0=0)
    {
        float4 h = make_float4(0.f, 0.f, 0.f, 0.f);
#pragma unroll
        for (int t0 = 0; t0 < LL; t0 += 8) {
            float4 v[8];
#pragma unroll
            for (int u = 0; u < 8; ++u) v[u] = xp[(size_t)(t0 + u) * (DD / 4)];
#pragma unroll
            for (int u = 0; u < 8; ++u) h = fma4(h, a, v[u]);
        }
        ((float4*)carry)[((size_t)b * CC + c) * (DD / 4) + i4] = h;
    }

    // ---- phase 1b: BC transpose+cast, 2 of the 1024 32x32 tiles per block
    {
        const int tx = threadIdx.x & 31;
        const int ty = threadIdx.x >> 5;   // 0..7
#pragma unroll
        for (int w = 0; w < 2; ++w) {
            const int t = id * 2 + w;
            const int o0 = (t & 31) * 32;
            const int d0 = (t >> 5) * 32;
            __syncthreads();               // tile reuse across w
#pragma unroll
            for (int i = 0; i < 4; ++i) {
                const int dd = ty + i * 8;
                tile[dd][tx] = BC[(size_t)(d0 + dd) * OO + o0 + tx];
            }
            __syncthreads();
#pragma unroll
            for (int i = 0; i < 4; ++i) {
                const int oo = ty + i * 8;
                BCt[(size_t)(o0 + oo) * DD + d0 + tx] = (__bf16)tile[tx][oo];
            }
        }
    }

    // ---- all carries + BCt visible device-wide
    cg::this_grid().sync();

    // ---- phase 2: chunk prefix from carries, rescan x (L3-hot), emit hs
    float4 aL = a;
#pragma unroll
    for (int i = 0; i < 5; ++i) { aL.x *= aL.x; aL.y *= aL.y; aL.z *= aL.z; aL.w *= aL.w; }
    float4 h = make_float4(0.f, 0.f, 0.f, 0.f);
    const float4* cp = (const float4*)carry + (size_t)b * CC * (DD / 4) + i4;
    for (int j = 0; j < c; ++j) {
        const float4 cv = cp[(size_t)j * (DD / 4)];
        h.x = fmaf(h.x, aL.x, cv.x);
        h.y = fmaf(h.y, aL.y, cv.y);
        h.z = fmaf(h.z, aL.z, cv.z);
        h.w = fmaf(h.w, aL.w, cv.w);
    }
    bf16x4* hp = (bf16x4*)(hs + base) + i4;
#pragma unroll
    for (int t0 = 0; t0 < LL; t0 += 8) {
        float4 v[8];
#pragma unroll
        for (int u = 0; u < 8; ++u) v[u] = xp[(size_t)(t0 + u) * (DD / 4)];
#pragma unroll
        for (int u = 0; u < 8; ++u) {
            h = fma4(h, a, v[u]);
            bf16x4 o;
            o[0] = (__bf16)h.x; o[1] = (__bf16)h.y; o[2] = (__bf16)h.z; o[3] = (__bf16)h.w;
            hp[(size_t)(t0 + u) * (DD / 4)] = o;
        }
    }
}

// ---------------- GEMM: C[m,n] = sum_k A[m,k] * Bt[n,k] ----------------
// (unchanged from round 4 — verified) 256x256 tile, BK=64, 8 waves (2Mx4N).
// ONE vmcnt(0) + ONE barrier per K-tile, all stages strictly AFTER the
// barrier (release: tile t-1's buf[nxt] ds_reads retired before barrier t;
// publish: vmcnt(0)+barrier before buf[cur] reads). XOR swizzle
// qs = qg ^ (rho&7): SQ_LDS_BANK_CONFLICT == 0 verified.
#define GTM 256
#define GTN 256
#define GTK 64
#define GNT (KK / GTK)   // 16

__device__ __forceinline__ void async16(void* lds, const void* g) {
    __builtin_amdgcn_global_load_lds(
        (__attribute__((address_space(1))) void*)(void*)g,
        (__attribute__((address_space(3))) void*)lds, 16, 0, 0);
}

#define MEMFENCE asm volatile("" ::: "memory")
#define BARRIER do { MEMFENCE; __builtin_amdgcn_s_barrier(); MEMFENCE; } while (0)
#define VMCNT0 asm volatile("s_waitcnt vmcnt(0)" ::: "memory")

__global__ __launch_bounds__(512, 2) void gemm_bt(const __bf16* __restrict__ Am,
                                                  const __bf16* __restrict__ Bt,
                                                  float* __restrict__ C) {
    __shared__ __align__(16) __bf16 As[2][GTM * GTK];   // 2 x 32 KB
    __shared__ __align__(16) __bf16 Bs[2][GTN * GTK];   // 2 x 32 KB

    const int tid = threadIdx.x;          // 0..511
    const int wave = tid >> 6;            // 0..7
    const int lane = tid & 63;
    const int wm = (wave >> 2) * 128;     // 0 / 128
    const int wn = (wave & 3) * 64;       // 0,64,128,192
    const int lanelo = lane & 15;
    const int quad = lane >> 4;

    // XCD-chunked swizzle (FETCH_SIZE 38->24.6 MB)
    const int bid = blockIdx.x;
    const int xcd = bid & 7;
    const int loc = bid >> 3;             // 0..31
    const int tile_m = (xcd * 8 + (loc >> 2)) * GTM;
    const int tile_n = (loc & 3) * GTN;

    // ---- staging pointers: slabs {0:A-M0, 1:B-N0, 2:B-N1, 3:A-M1} x 2 loads
    const __bf16* gsrc[4][2];
    int ldsoff[4][2];
#pragma unroll
    for (int a = 0; a < 2; ++a)
#pragma unroll
        for (int u = 0; u < 2; ++u) {
            const int idx = a * 1024 + u * 512 + tid;   // LDS chunk id
            const int rho = idx >> 3, qs = idx & 7;
            const int rl = rho & 127;
            const int r = (rl >> 6) * 128 + a * 64 + (rl & 63);  // global row
            const int qg = qs ^ (rho & 7);
            gsrc[a * 3][u] = Am + (size_t)(tile_m + r) * KK + qg * 8;
            ldsoff[a * 3][u] = idx * 8;
        }
#pragma unroll
    for (int b = 0; b < 2; ++b)
#pragma unroll
        for (int u = 0; u < 2; ++u) {
            const int idx = b * 1024 + u * 512 + tid;
            const int rho = idx >> 3, qs = idx & 7;
            const int rl = rho & 127;
            const int r = (rl >> 5) * 64 + b * 32 + (rl & 31);   // global row
            const int qg = qs ^ (rho & 7);
            gsrc[1 + b][u] = Bt + (size_t)(tile_n + r) * KK + qg * 8;
            ldsoff[1 + b][u] = idx * 8;
        }

    auto stage = [&](int p, int bufi, int koff) {
        __bf16* base = (p == 0 || p == 3) ? As[bufi] : Bs[bufi];
#pragma unroll
        for (int u = 0; u < 2; ++u)
            async16(base + ldsoff[p][u], gsrc[p][u] + koff);
    };

    floatx4 acc[8][4];
#pragma unroll
    for (int i = 0; i < 8; ++i)
#pragma unroll
        for (int j = 0; j < 4; ++j) acc[i][j] = (floatx4){0.f, 0.f, 0.f, 0.f};

    bf16x8 af[4][2];        // current M-half A fragments
    bf16x8 bv[2][2][2];     // [Nhalf][jl][kk], both halves held

    auto read_a = [&](const __bf16* as, int mh) {
#pragma unroll
        for (int il = 0; il < 4; ++il)
#pragma unroll
            for (int kk = 0; kk < 2; ++kk) {
                const int rho = mh * 128 + (wm >> 1) + il * 16 + lanelo;
                af[il][kk] = *(const bf16x8*)(as + rho * 64 + (((kk * 4 + quad) ^ (lanelo & 7)) * 8));
            }
    };
    auto read_b = [&](const __bf16* bs, int nh) {
#pragma unroll
        for (int jl = 0; jl < 2; ++jl)
#pragma unroll
            for (int kk = 0; kk < 2; ++kk) {
                const int rho = nh * 128 + (wn >> 1) + jl * 16 + lanelo;
                bv[nh][jl][kk] = *(const bf16x8*)(bs + rho * 64 + (((kk * 4 + quad) ^ (lanelo & 7)) * 8));
            }
    };
    auto mfma16 = [&](int mh, int nh) {
        __builtin_amdgcn_s_setprio(1);
#pragma unroll
        for (int il = 0; il < 4; ++il)
#pragma unroll
            for (int jl = 0; jl < 2; ++jl)
#pragma unroll
                for (int kk = 0; kk < 2; ++kk)
                    acc[mh * 4 + il][nh * 2 + jl] = __builtin_amdgcn_mfma_f32_16x16x32_bf16(
                        af[il][kk], bv[nh][jl][kk], acc[mh * 4 + il][nh * 2 + jl], 0, 0, 0);
        __builtin_amdgcn_s_setprio(0);
    };
    auto store_q = [&](int mh, int nh) {
#pragma unroll
        for (int il = 0; il < 4; ++il) {
            const int row = tile_m + wm + (mh * 4 + il) * 16 + quad * 4;
#pragma unroll
            for (int r = 0; r < 4; ++r) {
                float* crow = C + (size_t)(row + r) * NN + tile_n + wn + lanelo;
#pragma unroll
                for (int jl = 0; jl < 2; ++jl)
                    crow[(nh * 2 + jl) * 16] = acc[mh * 4 + il][nh * 2 + jl][r];
            }
        }
    };

    // prologue: tile 0, all 4 slabs -> buf 0 (8 loads in flight)
    stage(0, 0, 0);
    stage(3, 0, 0);
    stage(1, 0, 0);
    stage(2, 0, 0);

    for (int t = 0; t < GNT - 1; ++t) {
        const int cur = t & 1, nxt = cur ^ 1;
        const __bf16* as = As[cur];
        const __bf16* bs = Bs[cur];
        const int ko = (t + 1) * GTK;

        VMCNT0;                   // tile t's 8 loads retired (issued 1 tile ago)
        BARRIER;                  // publish tile t; release buf[nxt] for overwrite

        stage(0, nxt, ko);        // all stages AFTER the barrier
        stage(3, nxt, ko);
        stage(1, nxt, ko);
        stage(2, nxt, ko);

        read_a(as, 0);
        read_b(bs, 0);
        mfma16(0, 0);

        read_b(bs, 1);
        mfma16(0, 1);

        read_a(as, 1);
        mfma16(1, 1);

        mfma16(1, 0);
    }

    // tail tile: drain, then interleave quadrant stores with final MFMAs
    {
        const __bf16* as = As[(GNT - 1) & 1];
        const __bf16* bs = Bs[(GNT - 1) & 1];
        VMCNT0;
        BARRIER;
        read_a(as, 0);
        read_b(bs, 0);
        mfma16(0, 0);
        read_b(bs, 1);
        mfma16(0, 1);
        store_q(0, 0);            // acc[0..3][0..1] final
        read_a(as, 1);
        mfma16(1, 1);
        store_q(0, 1);            // acc[0..3][2..3] final
        mfma16(1, 0);
        store_q(1, 0);
        store_q(1, 1);
    }
}

extern "C" void kernel_launch(void* const* d_in, const int* in_sizes, int n_in,
                              void* d_out, int out_size, void* d_ws, size_t ws_size,
                              hipStream_t stream) {
    const float* x  = (const float*)d_in[0];   // [B,S,D]
    const float* A  = (const float*)d_in[1];   // [D]
    const float* BC = (const float*)d_in[2];   // [D,O]
    float* out = (float*)d_out;                // [B,S,O]

    char* ws = (char*)d_ws;
    __bf16* hs   = (__bf16*)ws;                                  // 33,554,432 B
    float* carry = (float*)(ws + 33554432);                      // 2 MB (BB*CC*DD*4)
    __bf16* BCt  = (__bf16*)(ws + 33554432 + 2097152);           // 2 MB

    void* args[] = {(void*)&x, (void*)&A, (void*)&carry, (void*)&BC, (void*)&BCt, (void*)&hs};
    hipLaunchCooperativeKernel((const void*)scan_full, dim3(BB * CC), dim3(256),
                               args, 0, stream);
    gemm_bt<<<dim3(MM / GTM * (NN / GTN)), 512, 0, stream>>>(hs, BCt, out);
}

// Round 6
// 166.726 us; speedup vs baseline: 1.4293x; 1.4293x over previous
//
#include <hip/hip_runtime.h>
#include <hip/hip_bf16.h>

// Problem constants
#define BB 8
#define SS 2048
#define DD 1024
#define OO 1024
#define MM (BB * SS)   // 16384
#define KK DD          // 1024
#define NN OO          // 1024
#define CC 64          // chunks
#define LL 32          // chunk length (CC*LL == SS)

typedef __bf16 bf16x8 __attribute__((ext_vector_type(8)));
typedef __bf16 bf16x2 __attribute__((ext_vector_type(2)));
typedef float floatx4 __attribute__((ext_vector_type(4)));

__device__ __forceinline__ float2 fma2(float2 h, float2 a, float2 v) {
    h.x = fmaf(h.x, a.x, v.x);
    h.y = fmaf(h.y, a.y, v.y);
    return h;
}

// ---------------- Kernel 1: per-chunk carries (float2 lanes, 512 thr) + BC transpose ----------------
// float2-per-thread: 512 threads/block -> 4096 waves total = 16 waves/CU
// (2x round-4's 8) to attack the measured latency-boundedness (round-5
// scan_full: VALUBusy 1.6%, HBM 16%, occupancy 19.5% => latency-bound).
// Element-wise fma chain identical to the float4 version -> same rounding.
__global__ __launch_bounds__(512) void prep(const float* __restrict__ x,
                                            const float* __restrict__ A,
                                            float* __restrict__ carry,
                                            const float* __restrict__ BC,
                                            __bf16* __restrict__ BCt) {
    __shared__ float tile[32][33];
    const int id = blockIdx.x;
    if (id < BB * CC) {
        const int c = id & (CC - 1);
        const int b = id >> 6;          // id / CC
        const int i2 = threadIdx.x;     // float2 index over D (0..511)
        const float2 a = ((const float2*)A)[i2];
        const float2* xp = (const float2*)(x + ((size_t)b * SS + (size_t)c * LL) * DD) + i2;
        float2 h = make_float2(0.f, 0.f);
#pragma unroll
        for (int t0 = 0; t0 < LL; t0 += 8) {
            float2 v[8];
#pragma unroll
            for (int u = 0; u < 8; ++u) v[u] = xp[(size_t)(t0 + u) * (DD / 2)];
#pragma unroll
            for (int u = 0; u < 8; ++u) h = fma2(h, a, v[u]);
        }
        ((float2*)carry)[((size_t)b * CC + c) * (DD / 2) + i2] = h;
    } else {
        const int t = id - BB * CC;        // 0..1023 transpose tiles
        const int o0 = (t & 31) * 32;
        const int d0 = (t >> 5) * 32;
        const int tx = threadIdx.x & 31;
        const int ty = threadIdx.x >> 5;   // 0..15
#pragma unroll
        for (int i = 0; i < 2; ++i) {
            const int dd = ty + i * 16;
            tile[dd][tx] = BC[(size_t)(d0 + dd) * OO + o0 + tx];
        }
        __syncthreads();
#pragma unroll
        for (int i = 0; i < 2; ++i) {
            const int oo = ty + i * 16;
            BCt[(size_t)(o0 + oo) * DD + d0 + tx] = (__bf16)tile[tx][oo];
        }
    }
}

// ---------------- Kernel 2: emit hs (bf16); prefix batched 8-deep ----------------
// Prefix loop: full batches of 8 independent carry loads in flight (was 1
// non-unrolled latency-serialized load/iter, worst-case 63 deep for c=63
// blocks -> straggler tail). Serial tail <= 7 iters. Same fma order.
__global__ __launch_bounds__(512) void scan_emit(const float* __restrict__ x,
                                                 const float* __restrict__ A,
                                                 const float* __restrict__ carry,
                                                 __bf16* __restrict__ hs) {
    const int id = blockIdx.x;
    const int c = id & (CC - 1);
    const int b = id >> 6;
    const int i2 = threadIdx.x;     // float2 index over D (0..511)
    const float2 a = ((const float2*)A)[i2];
    float2 aL = a;
#pragma unroll
    for (int i = 0; i < 5; ++i) { aL.x *= aL.x; aL.y *= aL.y; }   // a^32
    float2 h = make_float2(0.f, 0.f);
    const float2* cp = (const float2*)carry + (size_t)b * CC * (DD / 2) + i2;
    int j = 0;
    for (; j + 8 <= c; j += 8) {
        float2 cv[8];
#pragma unroll
        for (int u = 0; u < 8; ++u) cv[u] = cp[(size_t)(j + u) * (DD / 2)];
#pragma unroll
        for (int u = 0; u < 8; ++u) h = fma2(h, aL, cv[u]);
    }
    for (; j < c; ++j) h = fma2(h, aL, cp[(size_t)j * (DD / 2)]);

    const size_t base = ((size_t)b * SS + (size_t)c * LL) * DD;
    const float2* xp = (const float2*)(x + base) + i2;
    bf16x2* hp = (bf16x2*)(hs + base) + i2;
#pragma unroll
    for (int t0 = 0; t0 < LL; t0 += 8) {
        float2 v[8];
#pragma unroll
        for (int u = 0; u < 8; ++u) v[u] = xp[(size_t)(t0 + u) * (DD / 2)];
#pragma unroll
        for (int u = 0; u < 8; ++u) {
            h = fma2(h, a, v[u]);
            bf16x2 o;
            o[0] = (__bf16)h.x; o[1] = (__bf16)h.y;
            hp[(size_t)(t0 + u) * (DD / 2)] = o;
        }
    }
}

// ---------------- GEMM: C[m,n] = sum_k A[m,k] * Bt[n,k] ----------------
// (byte-identical to round 4 — verified 46.8 us, SQ_LDS_BANK_CONFLICT=0)
// 256x256 tile, BK=64, 8 waves (2Mx4N). ONE vmcnt(0) + ONE barrier per
// K-tile, all stages strictly AFTER the barrier.
#define GTM 256
#define GTN 256
#define GTK 64
#define GNT (KK / GTK)   // 16

__device__ __forceinline__ void async16(void* lds, const void* g) {
    __builtin_amdgcn_global_load_lds(
        (__attribute__((address_space(1))) void*)(void*)g,
        (__attribute__((address_space(3))) void*)lds, 16, 0, 0);
}

#define MEMFENCE asm volatile("" ::: "memory")
#define BARRIER do { MEMFENCE; __builtin_amdgcn_s_barrier(); MEMFENCE; } while (0)
#define VMCNT0 asm volatile("s_waitcnt vmcnt(0)" ::: "memory")

__global__ __launch_bounds__(512, 2) void gemm_bt(const __bf16* __restrict__ Am,
                                                  const __bf16* __restrict__ Bt,
                                                  float* __restrict__ C) {
    __shared__ __align__(16) __bf16 As[2][GTM * GTK];   // 2 x 32 KB
    __shared__ __align__(16) __bf16 Bs[2][GTN * GTK];   // 2 x 32 KB

    const int tid = threadIdx.x;          // 0..511
    const int wave = tid >> 6;            // 0..7
    const int lane = tid & 63;
    const int wm = (wave >> 2) * 128;     // 0 / 128
    const int wn = (wave & 3) * 64;       // 0,64,128,192
    const int lanelo = lane & 15;
    const int quad = lane >> 4;

    // XCD-chunked swizzle (FETCH_SIZE 38->24.6 MB)
    const int bid = blockIdx.x;
    const int xcd = bid & 7;
    const int loc = bid >> 3;             // 0..31
    const int tile_m = (xcd * 8 + (loc >> 2)) * GTM;
    const int tile_n = (loc & 3) * GTN;

    // ---- staging pointers: slabs {0:A-M0, 1:B-N0, 2:B-N1, 3:A-M1} x 2 loads
    const __bf16* gsrc[4][2];
    int ldsoff[4][2];
#pragma unroll
    for (int a = 0; a < 2; ++a)
#pragma unroll
        for (int u = 0; u < 2; ++u) {
            const int idx = a * 1024 + u * 512 + tid;   // LDS chunk id
            const int rho = idx >> 3, qs = idx & 7;
            const int rl = rho & 127;
            const int r = (rl >> 6) * 128 + a * 64 + (rl & 63);  // global row
            const int qg = qs ^ (rho & 7);
            gsrc[a * 3][u] = Am + (size_t)(tile_m + r) * KK + qg * 8;
            ldsoff[a * 3][u] = idx * 8;
        }
#pragma unroll
    for (int b = 0; b < 2; ++b)
#pragma unroll
        for (int u = 0; u < 2; ++u) {
            const int idx = b * 1024 + u * 512 + tid;
            const int rho = idx >> 3, qs = idx & 7;
            const int rl = rho & 127;
            const int r = (rl >> 5) * 64 + b * 32 + (rl & 31);   // global row
            const int qg = qs ^ (rho & 7);
            gsrc[1 + b][u] = Bt + (size_t)(tile_n + r) * KK + qg * 8;
            ldsoff[1 + b][u] = idx * 8;
        }

    auto stage = [&](int p, int bufi, int koff) {
        __bf16* base = (p == 0 || p == 3) ? As[bufi] : Bs[bufi];
#pragma unroll
        for (int u = 0; u < 2; ++u)
            async16(base + ldsoff[p][u], gsrc[p][u] + koff);
    };

    floatx4 acc[8][4];
#pragma unroll
    for (int i = 0; i < 8; ++i)
#pragma unroll
        for (int j = 0; j < 4; ++j) acc[i][j] = (floatx4){0.f, 0.f, 0.f, 0.f};

    bf16x8 af[4][2];        // current M-half A fragments
    bf16x8 bv[2][2][2];     // [Nhalf][jl][kk], both halves held

    auto read_a = [&](const __bf16* as, int mh) {
#pragma unroll
        for (int il = 0; il < 4; ++il)
#pragma unroll
            for (int kk = 0; kk < 2; ++kk) {
                const int rho = mh * 128 + (wm >> 1) + il * 16 + lanelo;
                af[il][kk] = *(const bf16x8*)(as + rho * 64 + (((kk * 4 + quad) ^ (lanelo & 7)) * 8));
            }
    };
    auto read_b = [&](const __bf16* bs, int nh) {
#pragma unroll
        for (int jl = 0; jl < 2; ++jl)
#pragma unroll
            for (int kk = 0; kk < 2; ++kk) {
                const int rho = nh * 128 + (wn >> 1) + jl * 16 + lanelo;
                bv[nh][jl][kk] = *(const bf16x8*)(bs + rho * 64 + (((kk * 4 + quad) ^ (lanelo & 7)) * 8));
            }
    };
    auto mfma16 = [&](int mh, int nh) {
        __builtin_amdgcn_s_setprio(1);
#pragma unroll
        for (int il = 0; il < 4; ++il)
#pragma unroll
            for (int jl = 0; jl < 2; ++jl)
#pragma unroll
                for (int kk = 0; kk < 2; ++kk)
                    acc[mh * 4 + il][nh * 2 + jl] = __builtin_amdgcn_mfma_f32_16x16x32_bf16(
                        af[il][kk], bv[nh][jl][kk], acc[mh * 4 + il][nh * 2 + jl], 0, 0, 0);
        __builtin_amdgcn_s_setprio(0);
    };
    auto store_q = [&](int mh, int nh) {
#pragma unroll
        for (int il = 0; il < 4; ++il) {
            const int row = tile_m + wm + (mh * 4 + il) * 16 + quad * 4;
#pragma unroll
            for (int r = 0; r < 4; ++r) {
                float* crow = C + (size_t)(row + r) * NN + tile_n + wn + lanelo;
#pragma unroll
                for (int jl = 0; jl < 2; ++jl)
                    crow[(nh * 2 + jl) * 16] = acc[mh * 4 + il][nh * 2 + jl][r];
            }
        }
    };

    // prologue: tile 0, all 4 slabs -> buf 0 (8 loads in flight)
    stage(0, 0, 0);
    stage(3, 0, 0);
    stage(1, 0, 0);
    stage(2, 0, 0);

    for (int t = 0; t < GNT - 1; ++t) {
        const int cur = t & 1, nxt = cur ^ 1;
        const __bf16* as = As[cur];
        const __bf16* bs = Bs[cur];
        const int ko = (t + 1) * GTK;

        VMCNT0;                   // tile t's 8 loads retired (issued 1 tile ago)
        BARRIER;                  // publish tile t; release buf[nxt] for overwrite

        stage(0, nxt, ko);        // all stages AFTER the barrier
        stage(3, nxt, ko);
        stage(1, nxt, ko);
        stage(2, nxt, ko);

        read_a(as, 0);
        read_b(bs, 0);
        mfma16(0, 0);

        read_b(bs, 1);
        mfma16(0, 1);

        read_a(as, 1);
        mfma16(1, 1);

        mfma16(1, 0);
    }

    // tail tile: drain, then interleave quadrant stores with final MFMAs
    {
        const __bf16* as = As[(GNT - 1) & 1];
        const __bf16* bs = Bs[(GNT - 1) & 1];
        VMCNT0;
        BARRIER;
        read_a(as, 0);
        read_b(bs, 0);
        mfma16(0, 0);
        read_b(bs, 1);
        mfma16(0, 1);
        store_q(0, 0);            // acc[0..3][0..1] final
        read_a(as, 1);
        mfma16(1, 1);
        store_q(0, 1);            // acc[0..3][2..3] final
        mfma16(1, 0);
        store_q(1, 0);
        store_q(1, 1);
    }
}

extern "C" void kernel_launch(void* const* d_in, const int* in_sizes, int n_in,
                              void* d_out, int out_size, void* d_ws, size_t ws_size,
                              hipStream_t stream) {
    const float* x  = (const float*)d_in[0];   // [B,S,D]
    const float* A  = (const float*)d_in[1];   // [D]
    const float* BC = (const float*)d_in[2];   // [D,O]
    float* out = (float*)d_out;                // [B,S,O]

    char* ws = (char*)d_ws;
    __bf16* hs   = (__bf16*)ws;                                  // 33,554,432 B
    float* carry = (float*)(ws + 33554432);                      // 2 MB (BB*CC*DD*4)
    __bf16* BCt  = (__bf16*)(ws + 33554432 + 2097152);           // 2 MB

    prep<<<dim3(BB * CC + 1024), 512, 0, stream>>>(x, A, carry, BC, BCt);
    scan_emit<<<dim3(BB * CC), 512, 0, stream>>>(x, A, carry, hs);
    gemm_bt<<<dim3(MM / GTM * (NN / GTN)), 512, 0, stream>>>(hs, BCt, out);
}